// Round 2
// 2051.953 us; speedup vs baseline: 1.0551x; 1.0551x over previous
//
#include <hip/hip_runtime.h>

typedef __bf16 bf16_t;
typedef __bf16 bf16x8 __attribute__((ext_vector_type(8)));
typedef float f32x4 __attribute__((ext_vector_type(4)));

#define SQH 0.70710678118654752440f

__device__ __forceinline__ void gld_lds16(const bf16_t* g, bf16_t* l) {
  __builtin_amdgcn_global_load_lds(
      (__attribute__((address_space(1))) void*)(void*)(g),
      (__attribute__((address_space(3))) void*)(l), 16, 0, 0);
}

// ---------------------------------------------------------------------------
// NT GEMM: C[M,N] = A[M,K] * B[N,K]^T (+bias). A rows optionally remapped:
//   arow = m + pad2*(m>>clog2) + bshift + (k0>>seglog2), acol = k0 & mask
// MODE 0: plain epilogue -> optional f32 Cf (ldc) and/or bf16 Cb (ldcb, row remap)
// MODE 1: fused GLU (cols interleaved a/g): even cols a, odd cols g;
//         writes f32 Cf[row*1024 + col/2] and bf16 Cb[row*1024 + col/2]
// MODE 2: fused combine: Cb = (v + aux0[row*ldc+col]) * SQH   (bf16)
// MODE 3: fused residual: nv = ((aux0 + v)*SQH + aux1)*SQH;
//         aux1[row*ldc+col] = nv (f32), Cb[remap(row)*ldcb+col] = nv (bf16)
// ---------------------------------------------------------------------------
template<int MODE>
__global__ __launch_bounds__(256, 2)
void k_gemm_nt(const bf16_t* __restrict__ A, const bf16_t* __restrict__ B,
               const float* __restrict__ bias,
               float* __restrict__ Cf, bf16_t* __restrict__ Cb,
               const float* __restrict__ aux0, float* __restrict__ aux1,
               int K, int lda, int ldb, int ldc, int ldcb,
               int pad2, int bshift, int seglog2, int clog2,
               int cbpad2, int cbshift,
               long long saB, long long sbB, long long scB)
{
  __shared__ __align__(16) bf16_t sA[128 * 32];
  __shared__ __align__(16) bf16_t sB[128 * 32];

  const int tid  = threadIdx.x;
  const int wave = tid >> 6;
  const int lane = tid & 63;
  const int z    = blockIdx.z;
  A += (long long)z * saB;
  B += (long long)z * sbB;
  if (Cf) Cf += (long long)z * scB;
  if (Cb) Cb += (long long)z * scB;

  const int m0 = blockIdx.y * 128;
  const int n0 = blockIdx.x * 128;

  const int rq = tid >> 2;        // staging row 0..63 (and +64)
  const int qo = (tid & 3) * 8;   // 8-elem (16B) chunk within 32-elem row

  bf16_t* lA0 = sA + wave * 512;
  bf16_t* lA1 = sA + 2048 + wave * 512;
  bf16_t* lB0 = sB + wave * 512;
  bf16_t* lB1 = sB + 2048 + wave * 512;

  const int wm = (wave & 1) * 64;
  const int wn = (wave >> 1) * 64;
  const int lm = lane & 15;
  const int lk = (lane >> 4) * 8;

  f32x4 acc[4][4] = {};
  const int kmask = (1 << seglog2) - 1;

  for (int k0 = 0; k0 < K; k0 += 32) {
    const int kseg = k0 >> seglog2;
    const int kcol = k0 & kmask;
    {
      const int m1 = m0 + rq;
      const int m2 = m1 + 64;
      const long long ar1 = m1 + pad2 * (m1 >> clog2) + bshift + kseg;
      const long long ar2 = m2 + pad2 * (m2 >> clog2) + bshift + kseg;
      gld_lds16(A + ar1 * lda + kcol + qo, lA0);
      gld_lds16(A + ar2 * lda + kcol + qo, lA1);
      const long long nr = n0 + rq;
      gld_lds16(B + nr * ldb + k0 + qo, lB0);
      gld_lds16(B + (nr + 64) * ldb + k0 + qo, lB1);
    }
    __syncthreads();
    bf16x8 af[4], bfr[4];
#pragma unroll
    for (int i = 0; i < 4; ++i)
      af[i] = *(const bf16x8*)(sA + (wm + i * 16 + lm) * 32 + lk);
#pragma unroll
    for (int j = 0; j < 4; ++j)
      bfr[j] = *(const bf16x8*)(sB + (wn + j * 16 + lm) * 32 + lk);
#pragma unroll
    for (int i = 0; i < 4; ++i)
#pragma unroll
      for (int j = 0; j < 4; ++j)
        acc[i][j] = __builtin_amdgcn_mfma_f32_16x16x32_bf16(af[i], bfr[j], acc[i][j], 0, 0, 0);
    __syncthreads();
  }

  const int lq = (lane >> 4) * 4;
#pragma unroll
  for (int i = 0; i < 4; ++i) {
#pragma unroll
    for (int j = 0; j < 4; ++j) {
      const int col = n0 + wn + j * 16 + lm;
      const float bv = bias ? bias[col] : 0.0f;
#pragma unroll
      for (int r = 0; r < 4; ++r) {
        const int row = m0 + wm + i * 16 + lq + r;
        float v = acc[i][j][r] + bv;
        if constexpr (MODE == 0) {
          if (Cf) Cf[(long long)row * ldc + col] = v;
          if (Cb) {
            const long long brow = row + cbpad2 * (row >> clog2) + cbshift;
            Cb[brow * ldcb + col] = (bf16_t)v;
          }
        } else if constexpr (MODE == 1) {
          // interleaved cols: even = a, odd = g. Pair via lane^1 (col low bit == lane low bit).
          float p = __shfl_xor(v, 1);
          if (!(lane & 1)) {
            float res = v * (1.f / (1.f + __expf(-p)));
            const int h = col >> 1;
            Cf[(long long)row * 1024 + h] = res;
            Cb[(long long)row * 1024 + h] = (bf16_t)res;
          }
        } else if constexpr (MODE == 2) {
          float c = (v + aux0[(long long)row * ldc + col]) * SQH;
          Cb[(long long)row * ldcb + col] = (bf16_t)c;
        } else {  // MODE == 3
          const long long idx = (long long)row * ldc + col;
          float nv = ((aux0[idx] + v) * SQH + aux1[idx]) * SQH;
          aux1[idx] = nv;
          const long long brow = row + cbpad2 * (row >> clog2) + cbshift;
          Cb[brow * ldcb + col] = (bf16_t)nv;
        }
      }
    }
  }
}

// ---------------------------------------------------------------------------
// Setup / elementwise kernels
// ---------------------------------------------------------------------------
__global__ void k_transpose(const float* __restrict__ in, bf16_t* __restrict__ out,
                            int R, int C, long long sIn, long long sOut) {
  __shared__ float tile[32][33];
  const int b = blockIdx.z;
  in  += (long long)b * sIn;
  out += (long long)b * sOut;
  const int c0 = blockIdx.x * 32;
  const int r0 = blockIdx.y * 32;
  const int tx = threadIdx.x;
  for (int i = threadIdx.y; i < 32; i += 8) {
    int r = r0 + i, c = c0 + tx;
    tile[i][tx] = (r < R && c < C) ? in[(long long)r * C + c] : 0.f;
  }
  __syncthreads();
  for (int i = threadIdx.y; i < 32; i += 8) {
    int c = c0 + i, r = r0 + tx;
    if (c < C && r < R) out[(long long)c * R + r] = (bf16_t)tile[tx][i];
  }
}

__global__ void k_convert(const float* __restrict__ in, bf16_t* __restrict__ out, int n) {
  int i = blockIdx.x * 256 + threadIdx.x;
  if (i < n) out[i] = (bf16_t)in[i];
}

// conv_w (L,2H,H,3) -> bf16 (L, 2H interleaved a/g, 3*H) with [l][onew][k*1024+i]
// onew: o<1024 (a_h) -> 2h ; o>=1024 (g_h) -> 2h+1
__global__ void k_convw(const float* __restrict__ in, bf16_t* __restrict__ out) {
  const long long s = blockIdx.y;                  // l*2048+o, 0..12287
  const int i = blockIdx.x * 256 + threadIdx.x;    // 0..1023
  const float* p = in + s * 3072 + (long long)i * 3;
  float w0 = p[0], w1 = p[1], w2 = p[2];
  const int l = (int)(s >> 11);
  const int o = (int)(s & 2047);
  const int onew = (o < 1024) ? (o << 1) : (((o - 1024) << 1) | 1);
  bf16_t* q = out + ((long long)(l << 11) + onew) * 3072;
  q[i] = (bf16_t)w0; q[1024 + i] = (bf16_t)w1; q[2048 + i] = (bf16_t)w2;
}

// conv_b (L,2H) -> interleaved f32 (L,2H)
__global__ void k_convb(const float* __restrict__ in, float* __restrict__ out) {
  const int i = blockIdx.x * 256 + threadIdx.x;   // 0..12287
  const int l = i >> 11;
  const int o = i & 2047;
  const int onew = (o < 1024) ? (o << 1) : (((o - 1024) << 1) | 1);
  out[(l << 11) + onew] = in[i];
}

__global__ void k_embed(const int* __restrict__ trg, const float* __restrict__ tok,
                        const float* __restrict__ pos,
                        float* __restrict__ embF, bf16_t* __restrict__ embB) {
  const long long bt = blockIdx.x;   // 0..4095
  const int t = (int)(bt & 511);
  const int id = trg[bt];
  const float* tp = tok + (long long)id * 512;
  const float* pp = pos + (long long)t * 512;
  for (int j = threadIdx.x; j < 512; j += 256) {
    float v = tp[j] + pp[j];
    embF[bt * 512 + j] = v;
    embB[bt * 512 + j] = (bf16_t)v;
  }
}

__global__ void k_padinit(bf16_t* __restrict__ Xp) {
  const int i = blockIdx.x * 256 + threadIdx.x;  // 16384 = 8*2*1024
  const int b = i >> 11;
  const int r = (i >> 10) & 1;
  const int h = i & 1023;
  Xp[((long long)b * 514 + r) * 1024 + h] = (bf16_t)1.0f;  // PAD_IDX=1 quirk
}

__global__ void k_softmax(const float* __restrict__ E, bf16_t* __restrict__ A) {
  __shared__ float red[8];
  const long long m = blockIdx.x;
  const float* row = E + m * 512;
  const int t = threadIdx.x;
  float x0 = row[t], x1 = row[t + 256];
  float mx = fmaxf(x0, x1);
#pragma unroll
  for (int o = 32; o >= 1; o >>= 1) mx = fmaxf(mx, __shfl_xor(mx, o));
  const int w = t >> 6;
  if ((t & 63) == 0) red[w] = mx;
  __syncthreads();
  mx = fmaxf(fmaxf(red[0], red[1]), fmaxf(red[2], red[3]));
  float e0 = __expf(x0 - mx), e1 = __expf(x1 - mx);
  float s = e0 + e1;
#pragma unroll
  for (int o = 32; o >= 1; o >>= 1) s += __shfl_xor(s, o);
  if ((t & 63) == 0) red[4 + w] = s;
  __syncthreads();
  s = red[4] + red[5] + red[6] + red[7];
  float inv = 1.f / s;
  A[m * 512 + t]       = (bf16_t)(e0 * inv);
  A[m * 512 + t + 256] = (bf16_t)(e1 * inv);
}

// ---------------------------------------------------------------------------
extern "C" void kernel_launch(void* const* d_in, const int* in_sizes, int n_in,
                              void* d_out, int out_size, void* d_ws, size_t ws_size,
                              hipStream_t stream) {
  (void)in_sizes; (void)n_in; (void)out_size; (void)ws_size;
  const int*   trg    = (const int*)  d_in[0];
  const float* encCv  = (const float*)d_in[1];
  const float* encCb  = (const float*)d_in[2];
  const float* tokE   = (const float*)d_in[3];
  const float* posE   = (const float*)d_in[4];
  const float* e2h_w  = (const float*)d_in[5];
  const float* e2h_b  = (const float*)d_in[6];
  const float* h2e_w  = (const float*)d_in[7];
  const float* h2e_b  = (const float*)d_in[8];
  const float* ah2e_w = (const float*)d_in[9];
  const float* ah2e_b = (const float*)d_in[10];
  const float* ae2h_w = (const float*)d_in[11];
  const float* ae2h_b = (const float*)d_in[12];
  const float* fc_w   = (const float*)d_in[13];
  const float* fc_b   = (const float*)d_in[14];
  const float* convW  = (const float*)d_in[15];
  const float* convB  = (const float*)d_in[16];
  float* out = (float*)d_out;

  char* cur = (char*)d_ws;
  auto alloc = [&](long long bytes) { char* r = cur; cur += (bytes + 255) & ~255LL; return (void*)r; };

  bf16_t* embA    = (bf16_t*)alloc(4096LL * 512 * 2);
  bf16_t* Xpad    = (bf16_t*)alloc(8LL * 514 * 1024 * 2);
  bf16_t* convedB = (bf16_t*)alloc(4096LL * 1024 * 2);
  bf16_t* combB   = (bf16_t*)alloc(4096LL * 512 * 2);
  bf16_t* attnB   = (bf16_t*)alloc(4096LL * 512 * 2);
  bf16_t* attdB   = (bf16_t*)alloc(4096LL * 512 * 2);
  bf16_t* coutB   = (bf16_t*)alloc(4096LL * 512 * 2);
  bf16_t* wT_e2h  = (bf16_t*)alloc(1024LL * 512 * 2);
  bf16_t* wT_ah2e = (bf16_t*)alloc(512LL * 1024 * 2);
  bf16_t* wT_ae2h = (bf16_t*)alloc(1024LL * 512 * 2);
  bf16_t* wT_h2e  = (bf16_t*)alloc(512LL * 1024 * 2);
  bf16_t* wT_fc   = (bf16_t*)alloc(32000LL * 512 * 2);
  bf16_t* encCvB  = (bf16_t*)alloc(8LL * 512 * 512 * 2);
  bf16_t* encTcb  = (bf16_t*)alloc(8LL * 512 * 512 * 2);
  bf16_t* convWT  = (bf16_t*)alloc(6LL * 2048 * 3072 * 2);
  float*  biasI   = (float*)alloc(6LL * 2048 * 4);
  float*  embF    = (float*)alloc(4096LL * 512 * 4);
  float*  Xf      = (float*)alloc(4096LL * 1024 * 4);
  float*  convedF = (float*)alloc(4096LL * 1024 * 4);
  float*  energy  = (float*)alloc(4096LL * 512 * 4);

  const dim3 tb(32, 8);
  k_transpose<<<dim3(32, 16, 1),  tb, 0, stream>>>(e2h_w,  wT_e2h,  512, 1024, 0, 0);
  k_transpose<<<dim3(16, 32, 1),  tb, 0, stream>>>(ah2e_w, wT_ah2e, 1024, 512, 0, 0);
  k_transpose<<<dim3(32, 16, 1),  tb, 0, stream>>>(ae2h_w, wT_ae2h, 512, 1024, 0, 0);
  k_transpose<<<dim3(16, 32, 1),  tb, 0, stream>>>(h2e_w,  wT_h2e,  1024, 512, 0, 0);
  k_transpose<<<dim3(1000, 16, 1),tb, 0, stream>>>(fc_w,   wT_fc,   512, 32000, 0, 0);
  k_transpose<<<dim3(16, 16, 8),  tb, 0, stream>>>(encCb,  encTcb,  512, 512, 512LL * 512, 512LL * 512);
  k_convert<<<8192, 256, 0, stream>>>(encCv, encCvB, 8 * 512 * 512);
  k_convw<<<dim3(4, 12288), 256, 0, stream>>>(convW, convWT);
  k_convb<<<48, 256, 0, stream>>>(convB, biasI);
  k_embed<<<4096, 256, 0, stream>>>(trg, tokE, posE, embF, embA);
  k_padinit<<<64, 256, 0, stream>>>(Xpad);

  auto gemm0 = [&](const bf16_t* A, const bf16_t* B, const float* bias,
                   float* Cf, bf16_t* Cb, int M, int N, int K,
                   int lda, int ldb, int ldc, int ldcb,
                   int pad2, int bshift, int seglog2,
                   int cbpad2, int cbshift,
                   long long saB, long long sbB, long long scB, int Z) {
    dim3 g(N / 128, M / 128, Z);
    k_gemm_nt<0><<<g, 256, 0, stream>>>(A, B, bias, Cf, Cb, nullptr, nullptr,
                                        K, lda, ldb, ldc, ldcb,
                                        pad2, bshift, seglog2, 9, cbpad2, cbshift,
                                        saB, sbB, scB);
  };

  // emb2hid: X = embA @ e2h_w -> Xf (f32) + Xpad (bf16, rows shifted +2 per b)
  gemm0(embA, wT_e2h, e2h_b, Xf, Xpad, 4096, 1024, 512,
        512, 512, 1024, 1024, 0, 0, 30, 2, 2, 0, 0, 0, 1);

  for (int l = 0; l < 6; ++l) {
    // conv as one NT GEMM, K=3072 (3 segments of 1024, A row += segment idx),
    // fused GLU epilogue -> convedF (f32) + convedB (bf16)
    k_gemm_nt<1><<<dim3(16, 32, 1), 256, 0, stream>>>(
        Xpad, convWT + (long long)l * 2048 * 3072, biasI + l * 2048,
        convedF, convedB, nullptr, nullptr,
        3072, 1024, 3072, 1024, 1024, 2, 0, 10, 9, 0, 0, 0, 0, 0);
    // ah2e + fused combine: combB = (conved@W + b + embF) * SQH  (bf16)
    k_gemm_nt<2><<<dim3(4, 32, 1), 256, 0, stream>>>(
        convedB, wT_ah2e, ah2e_b, nullptr, combB, embF, nullptr,
        1024, 1024, 1024, 512, 512, 0, 0, 30, 9, 0, 0, 0, 0, 0);
    // energy: combined[b] (T,E) @ enc_conved[b]^T -> (T,S), batched over b
    gemm0(combB, encCvB, nullptr, energy, nullptr, 512, 512, 512,
          512, 512, 512, 0, 0, 0, 30, 0, 0, 512LL * 512, 512LL * 512, 512LL * 512, 8);
    k_softmax<<<4096, 256, 0, stream>>>(energy, attnB);
    // attended: attn[b] (T,S) @ encT_combined[b] (E,S)^T -> (T,E) bf16
    gemm0(attnB, encTcb, nullptr, nullptr, attdB, 512, 512, 512,
          512, 512, 512, 512, 0, 0, 30, 0, 0, 512LL * 512, 512LL * 512, 512LL * 512, 8);
    // ae2h + fused residual: X = ((conved + att2)*SQH + X)*SQH -> Xf + Xpad
    k_gemm_nt<3><<<dim3(8, 32, 1), 256, 0, stream>>>(
        attdB, wT_ae2h, ae2h_b, nullptr, Xpad, convedF, Xf,
        512, 512, 512, 1024, 1024, 0, 0, 30, 9, 2, 2, 0, 0, 0);
  }

  // hid2emb from Xpad (+2-shifted rows) -> bf16 conv_output
  gemm0(Xpad, wT_h2e, h2e_b, nullptr, coutB, 4096, 512, 1024,
        1024, 1024, 512, 512, 2, 2, 30, 0, 0, 0, 0, 0, 1);
  // fc_out -> d_out (f32)
  gemm0(coutB, wT_fc, fc_b, out, nullptr, 4096, 32000, 512,
        512, 512, 32000, 0, 0, 0, 30, 0, 0, 0, 0, 0, 1);
}

// Round 3
// 2049.288 us; speedup vs baseline: 1.0565x; 1.0013x over previous
//
#include <hip/hip_runtime.h>

typedef __bf16 bf16_t;
typedef __bf16 bf16x8 __attribute__((ext_vector_type(8)));
typedef float f32x4 __attribute__((ext_vector_type(4)));

#define SQH 0.70710678118654752440f

__device__ __forceinline__ void gld_lds16(const bf16_t* g, bf16_t* l) {
  __builtin_amdgcn_global_load_lds(
      (__attribute__((address_space(1))) void*)(void*)(g),
      (__attribute__((address_space(3))) void*)(l), 16, 0, 0);
}

// ---------------------------------------------------------------------------
// NT GEMM: C[M,N] = A[M,K] * B[N,K]^T (+bias). A rows optionally remapped:
//   arow = m + pad2*(m>>clog2) + bshift + (k0>>seglog2), acol = k0 & mask
// 2-phase pipelined: double-buffered LDS, tile t+1 staged (global_load_lds
// issued) BEFORE ds_read+MFMA of tile t; one barrier per K-step.
// MODE 0: plain epilogue -> optional f32 Cf (ldc) and/or bf16 Cb (ldcb, row remap)
// MODE 1: fused GLU (cols interleaved a/g): even cols a, odd cols g;
//         writes f32 Cf[row*1024 + col/2] and bf16 Cb[row*1024 + col/2]
// MODE 2: fused combine: Cb = (v + aux0[row*ldc+col]) * SQH   (bf16)
// MODE 3: fused residual: nv = ((aux0 + v)*SQH + aux1)*SQH;
//         aux1[row*ldc+col] = nv (f32), Cb[remap(row)*ldcb+col] = nv (bf16)
// ---------------------------------------------------------------------------
template<int MODE>
__global__ __launch_bounds__(256, 3)
void k_gemm_nt(const bf16_t* __restrict__ A, const bf16_t* __restrict__ B,
               const float* __restrict__ bias,
               float* __restrict__ Cf, bf16_t* __restrict__ Cb,
               const float* __restrict__ aux0, float* __restrict__ aux1,
               int K, int lda, int ldb, int ldc, int ldcb,
               int pad2, int bshift, int seglog2, int clog2,
               int cbpad2, int cbshift,
               long long saB, long long sbB, long long scB)
{
  __shared__ __align__(16) bf16_t sA[2][128 * 32];
  __shared__ __align__(16) bf16_t sB[2][128 * 32];

  const int tid  = threadIdx.x;
  const int wave = tid >> 6;
  const int lane = tid & 63;
  const int z    = blockIdx.z;
  A += (long long)z * saB;
  B += (long long)z * sbB;
  if (Cf) Cf += (long long)z * scB;
  if (Cb) Cb += (long long)z * scB;

  const int m0 = blockIdx.y * 128;
  const int n0 = blockIdx.x * 128;

  const int rq = tid >> 2;        // staging row 0..63 (and +64)
  const int qo = (tid & 3) * 8;   // 8-elem (16B) chunk within 32-elem row

  const int wm = (wave & 1) * 64;
  const int wn = (wave >> 1) * 64;
  const int lm = lane & 15;
  const int lk = (lane >> 4) * 8;

  f32x4 acc[4][4] = {};
  const int kmask = (1 << seglog2) - 1;

  auto stage = [&](int k0, bf16_t* dA, bf16_t* dB) {
    const int kseg = k0 >> seglog2;
    const int kcol = k0 & kmask;
    const int m1 = m0 + rq;
    const int m2 = m1 + 64;
    const long long ar1 = m1 + pad2 * (m1 >> clog2) + bshift + kseg;
    const long long ar2 = m2 + pad2 * (m2 >> clog2) + bshift + kseg;
    gld_lds16(A + ar1 * lda + kcol + qo, dA + wave * 512);
    gld_lds16(A + ar2 * lda + kcol + qo, dA + 2048 + wave * 512);
    const long long nr = n0 + rq;
    gld_lds16(B + nr * ldb + k0 + qo, dB + wave * 512);
    gld_lds16(B + (nr + 64) * ldb + k0 + qo, dB + 2048 + wave * 512);
  };

  const int nt = K >> 5;
  stage(0, sA[0], sB[0]);
  __syncthreads();          // vmcnt(0) drain: tile 0 resident

  int cur = 0;
  for (int t = 0; t < nt; ++t) {
    if (t + 1 < nt) stage((t + 1) << 5, sA[cur ^ 1], sB[cur ^ 1]);  // issue-early
    const bf16_t* pA = sA[cur];
    const bf16_t* pB = sB[cur];
    bf16x8 af[4], bfr[4];
#pragma unroll
    for (int i = 0; i < 4; ++i)
      af[i] = *(const bf16x8*)(pA + (wm + i * 16 + lm) * 32 + lk);
#pragma unroll
    for (int j = 0; j < 4; ++j)
      bfr[j] = *(const bf16x8*)(pB + (wn + j * 16 + lm) * 32 + lk);
#pragma unroll
    for (int i = 0; i < 4; ++i)
#pragma unroll
      for (int j = 0; j < 4; ++j)
        acc[i][j] = __builtin_amdgcn_mfma_f32_16x16x32_bf16(af[i], bfr[j], acc[i][j], 0, 0, 0);
    if (t + 1 < nt) __syncthreads();  // prefetch landed + all reads of buf done
    cur ^= 1;
  }

  const int lq = (lane >> 4) * 4;
#pragma unroll
  for (int i = 0; i < 4; ++i) {
#pragma unroll
    for (int j = 0; j < 4; ++j) {
      const int col = n0 + wn + j * 16 + lm;
      const float bv = bias ? bias[col] : 0.0f;
#pragma unroll
      for (int r = 0; r < 4; ++r) {
        const int row = m0 + wm + i * 16 + lq + r;
        float v = acc[i][j][r] + bv;
        if constexpr (MODE == 0) {
          if (Cf) Cf[(long long)row * ldc + col] = v;
          if (Cb) {
            const long long brow = row + cbpad2 * (row >> clog2) + cbshift;
            Cb[brow * ldcb + col] = (bf16_t)v;
          }
        } else if constexpr (MODE == 1) {
          // interleaved cols: even = a, odd = g. Pair via lane^1 (col low bit == lane low bit).
          float p = __shfl_xor(v, 1);
          if (!(lane & 1)) {
            float res = v * (1.f / (1.f + __expf(-p)));
            const int h = col >> 1;
            Cf[(long long)row * 1024 + h] = res;
            Cb[(long long)row * 1024 + h] = (bf16_t)res;
          }
        } else if constexpr (MODE == 2) {
          float c = (v + aux0[(long long)row * ldc + col]) * SQH;
          Cb[(long long)row * ldcb + col] = (bf16_t)c;
        } else {  // MODE == 3
          const long long idx = (long long)row * ldc + col;
          float nv = ((aux0[idx] + v) * SQH + aux1[idx]) * SQH;
          aux1[idx] = nv;
          const long long brow = row + cbpad2 * (row >> clog2) + cbshift;
          Cb[brow * ldcb + col] = (bf16_t)nv;
        }
      }
    }
  }
}

// ---------------------------------------------------------------------------
// Setup / elementwise kernels
// ---------------------------------------------------------------------------
__global__ void k_transpose(const float* __restrict__ in, bf16_t* __restrict__ out,
                            int R, int C, long long sIn, long long sOut) {
  __shared__ float tile[32][33];
  const int b = blockIdx.z;
  in  += (long long)b * sIn;
  out += (long long)b * sOut;
  const int c0 = blockIdx.x * 32;
  const int r0 = blockIdx.y * 32;
  const int tx = threadIdx.x;
  for (int i = threadIdx.y; i < 32; i += 8) {
    int r = r0 + i, c = c0 + tx;
    tile[i][tx] = (r < R && c < C) ? in[(long long)r * C + c] : 0.f;
  }
  __syncthreads();
  for (int i = threadIdx.y; i < 32; i += 8) {
    int c = c0 + i, r = r0 + tx;
    if (c < C && r < R) out[(long long)c * R + r] = (bf16_t)tile[tx][i];
  }
}

__global__ void k_convert(const float* __restrict__ in, bf16_t* __restrict__ out, int n) {
  int i = blockIdx.x * 256 + threadIdx.x;
  if (i < n) out[i] = (bf16_t)in[i];
}

// conv_w (L,2H,H,3) -> bf16 (L, 2H interleaved a/g, 3*H) with [l][onew][k*1024+i]
// onew: o<1024 (a_h) -> 2h ; o>=1024 (g_h) -> 2h+1
__global__ void k_convw(const float* __restrict__ in, bf16_t* __restrict__ out) {
  const long long s = blockIdx.y;                  // l*2048+o, 0..12287
  const int i = blockIdx.x * 256 + threadIdx.x;    // 0..1023
  const float* p = in + s * 3072 + (long long)i * 3;
  float w0 = p[0], w1 = p[1], w2 = p[2];
  const int l = (int)(s >> 11);
  const int o = (int)(s & 2047);
  const int onew = (o < 1024) ? (o << 1) : (((o - 1024) << 1) | 1);
  bf16_t* q = out + ((long long)(l << 11) + onew) * 3072;
  q[i] = (bf16_t)w0; q[1024 + i] = (bf16_t)w1; q[2048 + i] = (bf16_t)w2;
}

// conv_b (L,2H) -> interleaved f32 (L,2H)
__global__ void k_convb(const float* __restrict__ in, float* __restrict__ out) {
  const int i = blockIdx.x * 256 + threadIdx.x;   // 0..12287
  const int l = i >> 11;
  const int o = i & 2047;
  const int onew = (o < 1024) ? (o << 1) : (((o - 1024) << 1) | 1);
  out[(l << 11) + onew] = in[i];
}

__global__ void k_embed(const int* __restrict__ trg, const float* __restrict__ tok,
                        const float* __restrict__ pos,
                        float* __restrict__ embF, bf16_t* __restrict__ embB) {
  const long long bt = blockIdx.x;   // 0..4095
  const int t = (int)(bt & 511);
  const int id = trg[bt];
  const float* tp = tok + (long long)id * 512;
  const float* pp = pos + (long long)t * 512;
  for (int j = threadIdx.x; j < 512; j += 256) {
    float v = tp[j] + pp[j];
    embF[bt * 512 + j] = v;
    embB[bt * 512 + j] = (bf16_t)v;
  }
}

__global__ void k_padinit(bf16_t* __restrict__ Xp) {
  const int i = blockIdx.x * 256 + threadIdx.x;  // 16384 = 8*2*1024
  const int b = i >> 11;
  const int r = (i >> 10) & 1;
  const int h = i & 1023;
  Xp[((long long)b * 514 + r) * 1024 + h] = (bf16_t)1.0f;  // PAD_IDX=1 quirk
}

__global__ void k_softmax(const float* __restrict__ E, bf16_t* __restrict__ A) {
  __shared__ float red[8];
  const long long m = blockIdx.x;
  const float* row = E + m * 512;
  const int t = threadIdx.x;
  float x0 = row[t], x1 = row[t + 256];
  float mx = fmaxf(x0, x1);
#pragma unroll
  for (int o = 32; o >= 1; o >>= 1) mx = fmaxf(mx, __shfl_xor(mx, o));
  const int w = t >> 6;
  if ((t & 63) == 0) red[w] = mx;
  __syncthreads();
  mx = fmaxf(fmaxf(red[0], red[1]), fmaxf(red[2], red[3]));
  float e0 = __expf(x0 - mx), e1 = __expf(x1 - mx);
  float s = e0 + e1;
#pragma unroll
  for (int o = 32; o >= 1; o >>= 1) s += __shfl_xor(s, o);
  if ((t & 63) == 0) red[4 + w] = s;
  __syncthreads();
  s = red[4] + red[5] + red[6] + red[7];
  float inv = 1.f / s;
  A[m * 512 + t]       = (bf16_t)(e0 * inv);
  A[m * 512 + t + 256] = (bf16_t)(e1 * inv);
}

// ---------------------------------------------------------------------------
extern "C" void kernel_launch(void* const* d_in, const int* in_sizes, int n_in,
                              void* d_out, int out_size, void* d_ws, size_t ws_size,
                              hipStream_t stream) {
  (void)in_sizes; (void)n_in; (void)out_size; (void)ws_size;
  const int*   trg    = (const int*)  d_in[0];
  const float* encCv  = (const float*)d_in[1];
  const float* encCb  = (const float*)d_in[2];
  const float* tokE   = (const float*)d_in[3];
  const float* posE   = (const float*)d_in[4];
  const float* e2h_w  = (const float*)d_in[5];
  const float* e2h_b  = (const float*)d_in[6];
  const float* h2e_w  = (const float*)d_in[7];
  const float* h2e_b  = (const float*)d_in[8];
  const float* ah2e_w = (const float*)d_in[9];
  const float* ah2e_b = (const float*)d_in[10];
  const float* ae2h_w = (const float*)d_in[11];
  const float* ae2h_b = (const float*)d_in[12];
  const float* fc_w   = (const float*)d_in[13];
  const float* fc_b   = (const float*)d_in[14];
  const float* convW  = (const float*)d_in[15];
  const float* convB  = (const float*)d_in[16];
  float* out = (float*)d_out;

  char* cur = (char*)d_ws;
  auto alloc = [&](long long bytes) { char* r = cur; cur += (bytes + 255) & ~255LL; return (void*)r; };

  bf16_t* embA    = (bf16_t*)alloc(4096LL * 512 * 2);
  bf16_t* Xpad    = (bf16_t*)alloc(8LL * 514 * 1024 * 2);
  bf16_t* convedB = (bf16_t*)alloc(4096LL * 1024 * 2);
  bf16_t* combB   = (bf16_t*)alloc(4096LL * 512 * 2);
  bf16_t* attnB   = (bf16_t*)alloc(4096LL * 512 * 2);
  bf16_t* attdB   = (bf16_t*)alloc(4096LL * 512 * 2);
  bf16_t* coutB   = (bf16_t*)alloc(4096LL * 512 * 2);
  bf16_t* wT_e2h  = (bf16_t*)alloc(1024LL * 512 * 2);
  bf16_t* wT_ah2e = (bf16_t*)alloc(512LL * 1024 * 2);
  bf16_t* wT_ae2h = (bf16_t*)alloc(1024LL * 512 * 2);
  bf16_t* wT_h2e  = (bf16_t*)alloc(512LL * 1024 * 2);
  bf16_t* wT_fc   = (bf16_t*)alloc(32000LL * 512 * 2);
  bf16_t* encCvB  = (bf16_t*)alloc(8LL * 512 * 512 * 2);
  bf16_t* encTcb  = (bf16_t*)alloc(8LL * 512 * 512 * 2);
  bf16_t* convWT  = (bf16_t*)alloc(6LL * 2048 * 3072 * 2);
  float*  biasI   = (float*)alloc(6LL * 2048 * 4);
  float*  embF    = (float*)alloc(4096LL * 512 * 4);
  float*  Xf      = (float*)alloc(4096LL * 1024 * 4);
  float*  convedF = (float*)alloc(4096LL * 1024 * 4);
  float*  energy  = (float*)alloc(4096LL * 512 * 4);

  const dim3 tb(32, 8);
  k_transpose<<<dim3(32, 16, 1),  tb, 0, stream>>>(e2h_w,  wT_e2h,  512, 1024, 0, 0);
  k_transpose<<<dim3(16, 32, 1),  tb, 0, stream>>>(ah2e_w, wT_ah2e, 1024, 512, 0, 0);
  k_transpose<<<dim3(32, 16, 1),  tb, 0, stream>>>(ae2h_w, wT_ae2h, 512, 1024, 0, 0);
  k_transpose<<<dim3(16, 32, 1),  tb, 0, stream>>>(h2e_w,  wT_h2e,  1024, 512, 0, 0);
  k_transpose<<<dim3(1000, 16, 1),tb, 0, stream>>>(fc_w,   wT_fc,   512, 32000, 0, 0);
  k_transpose<<<dim3(16, 16, 8),  tb, 0, stream>>>(encCb,  encTcb,  512, 512, 512LL * 512, 512LL * 512);
  k_convert<<<8192, 256, 0, stream>>>(encCv, encCvB, 8 * 512 * 512);
  k_convw<<<dim3(4, 12288), 256, 0, stream>>>(convW, convWT);
  k_convb<<<48, 256, 0, stream>>>(convB, biasI);
  k_embed<<<4096, 256, 0, stream>>>(trg, tokE, posE, embF, embA);
  k_padinit<<<64, 256, 0, stream>>>(Xpad);

  auto gemm0 = [&](const bf16_t* A, const bf16_t* B, const float* bias,
                   float* Cf, bf16_t* Cb, int M, int N, int K,
                   int lda, int ldb, int ldc, int ldcb,
                   int pad2, int bshift, int seglog2,
                   int cbpad2, int cbshift,
                   long long saB, long long sbB, long long scB, int Z) {
    dim3 g(N / 128, M / 128, Z);
    k_gemm_nt<0><<<g, 256, 0, stream>>>(A, B, bias, Cf, Cb, nullptr, nullptr,
                                        K, lda, ldb, ldc, ldcb,
                                        pad2, bshift, seglog2, 9, cbpad2, cbshift,
                                        saB, sbB, scB);
  };

  // emb2hid: X = embA @ e2h_w -> Xf (f32) + Xpad (bf16, rows shifted +2 per b)
  gemm0(embA, wT_e2h, e2h_b, Xf, Xpad, 4096, 1024, 512,
        512, 512, 1024, 1024, 0, 0, 30, 2, 2, 0, 0, 0, 1);

  for (int l = 0; l < 6; ++l) {
    // conv as one NT GEMM, K=3072 (3 segments of 1024, A row += segment idx),
    // fused GLU epilogue -> convedF (f32) + convedB (bf16)
    k_gemm_nt<1><<<dim3(16, 32, 1), 256, 0, stream>>>(
        Xpad, convWT + (long long)l * 2048 * 3072, biasI + l * 2048,
        convedF, convedB, nullptr, nullptr,
        3072, 1024, 3072, 1024, 1024, 2, 0, 10, 9, 0, 0, 0, 0, 0);
    // ah2e + fused combine: combB = (conved@W + b + embF) * SQH  (bf16)
    k_gemm_nt<2><<<dim3(4, 32, 1), 256, 0, stream>>>(
        convedB, wT_ah2e, ah2e_b, nullptr, combB, embF, nullptr,
        1024, 1024, 1024, 512, 512, 0, 0, 30, 9, 0, 0, 0, 0, 0);
    // energy: combined[b] (T,E) @ enc_conved[b]^T -> (T,S), batched over b
    gemm0(combB, encCvB, nullptr, energy, nullptr, 512, 512, 512,
          512, 512, 512, 0, 0, 0, 30, 0, 0, 512LL * 512, 512LL * 512, 512LL * 512, 8);
    k_softmax<<<4096, 256, 0, stream>>>(energy, attnB);
    // attended: attn[b] (T,S) @ encT_combined[b] (E,S)^T -> (T,E) bf16
    gemm0(attnB, encTcb, nullptr, nullptr, attdB, 512, 512, 512,
          512, 512, 512, 512, 0, 0, 30, 0, 0, 512LL * 512, 512LL * 512, 512LL * 512, 8);
    // ae2h + fused residual: X = ((conved + att2)*SQH + X)*SQH -> Xf + Xpad
    k_gemm_nt<3><<<dim3(8, 32, 1), 256, 0, stream>>>(
        attdB, wT_ae2h, ae2h_b, nullptr, Xpad, convedF, Xf,
        512, 512, 512, 1024, 1024, 0, 0, 30, 9, 2, 2, 0, 0, 0);
  }

  // hid2emb from Xpad (+2-shifted rows) -> bf16 conv_output
  gemm0(Xpad, wT_h2e, h2e_b, nullptr, coutB, 4096, 512, 1024,
        1024, 1024, 512, 512, 2, 2, 30, 0, 0, 0, 0, 0, 1);
  // fc_out -> d_out (f32)
  gemm0(coutB, wT_fc, fc_b, out, nullptr, 4096, 32000, 512,
        512, 512, 32000, 0, 0, 0, 30, 0, 0, 0, 0, 0, 1);
}